// Round 3
// baseline (95.486 us; speedup 1.0000x reference)
//
#include <hip/hip_runtime.h>

// DiscoveryNet: out[b] = 0.5 * sum over ordered off-diagonal pairs of
//   MLP([r, 1/r, 1/r^2]), r = max(dist, 0.05).  v depends only on r and is
//   symmetric => sum over unordered pairs of a 1-D function v(r).
// Plan: tabulate v(r) (TN+1 points) in ONE fused kernel (h1 staged in LDS),
//   then pairs do sqrt + linear interp.  Remaining wall time is dominated by
//   the harness's 256 MB d_ws 0xAA poison fill (~40 us/iter, not ours).

#define NPTS   512
#define HDIM   128
#define NBATCH 8
#define TN     8192               // intervals; table has TN+1 entries
#define R0     0.05f
#define RMAX   20.05f
#define DELTA  ((RMAX - R0) / (float)TN)
#define PB     130816             // 512*511/2 unordered pairs per batch
#define NCHUNK 128
#define CHUNK  1022               // PB / NCHUNK exact

__device__ __forceinline__ float silu_f(float x) {
    float e = __expf(-x);
    return x * __builtin_amdgcn_rcpf(1.0f + e);
}

// ---------------------------------------------------------------------------
// Fused table kernel: 257 blocks x 256 threads; block owns 32 entries.
// Phase A: h1L[el][h] = silu(feats(e) @ W1 + b1)  (16 KB LDS, coalesced W1).
// Phase B: wave owns 8 entries, lane owns k={2*lane,2*lane+1}; W2 row loads
//   coalesced float2; h1 operand wave-uniform -> LDS broadcast (no conflict).
// Also zeroes d_out (block 0) so pair kernel can atomicAdd.
// ---------------------------------------------------------------------------
__global__ __launch_bounds__(256) void table_kernel(
    const float* __restrict__ W1, const float* __restrict__ b1,
    const float* __restrict__ W2, const float* __restrict__ b2,
    const float* __restrict__ W3, const float* __restrict__ b3,
    float* __restrict__ tab, float* __restrict__ out)
{
    __shared__ float h1L[32][HDIM];          // 16 KB
    const int tid = threadIdx.x;
    if (blockIdx.x == 0 && tid < NBATCH) out[tid] = 0.0f;

    // ---- Phase A ----
    {
        const int h   = tid & 127;
        const int sub = tid >> 7;            // 0/1 -> entries [0,16) / [16,32)
        const float w1a = W1[h], w1b = W1[HDIM + h], w1c = W1[2 * HDIM + h];
        const float bb  = b1[h];
        const int e0 = blockIdx.x * 32 + sub * 16;
        #pragma unroll
        for (int g = 0; g < 16; ++g) {
            const float r    = R0 + (float)(e0 + g) * DELTA;
            const float rinv = __builtin_amdgcn_rcpf(r);
            const float pre  = fmaf(r, w1a,
                               fmaf(rinv, w1b,
                               fmaf(rinv * rinv, w1c, bb)));
            h1L[sub * 16 + g][h] = silu_f(pre);
        }
    }
    __syncthreads();

    // ---- Phase B ----
    const int lane = tid & 63;
    const int wave = __builtin_amdgcn_readfirstlane(tid >> 6);   // 0..3

    const float2* __restrict__ W2v = (const float2*)W2;
    const float2 b2v = ((const float2*)b2)[lane];
    float2 acc[8];
    #pragma unroll
    for (int g = 0; g < 8; ++g) acc[g] = b2v;

    #pragma unroll 4
    for (int h = 0; h < HDIM; ++h) {
        const float2 w2 = W2v[h * 64 + lane];
        #pragma unroll
        for (int g = 0; g < 8; ++g) {
            const float hv = h1L[wave * 8 + g][h];   // wave-uniform broadcast
            acc[g].x = fmaf(hv, w2.x, acc[g].x);
            acc[g].y = fmaf(hv, w2.y, acc[g].y);
        }
    }

    const float2 w3v  = ((const float2*)W3)[lane];
    const float bias3 = b3[0];
    const int ebase = blockIdx.x * 32 + wave * 8;
    #pragma unroll
    for (int g = 0; g < 8; ++g) {
        float s = silu_f(acc[g].x) * w3v.x + silu_f(acc[g].y) * w3v.y;
        #pragma unroll
        for (int o = 32; o; o >>= 1) s += __shfl_xor(s, o, 64);
        const int e = ebase + g;
        if (lane == 0 && e <= TN) tab[e] = s + bias3;
    }
}

// ---------------------------------------------------------------------------
// Pair kernel: unordered-pair enumeration (each pair once, scale = 1.0):
//   t < 130560: d=(t>>9)+1 in [1,255], i=t&511, j=(i+d)&511
//   else:       antipodal (i, i+256), i = t-130560 in [0,256)
// ---------------------------------------------------------------------------
__global__ __launch_bounds__(256) void pair_sum_kernel(
    const float* __restrict__ pos, const float* __restrict__ tab,
    float* __restrict__ out)
{
    const int b = blockIdx.x >> 7;          // batch
    const int c = blockIdx.x & (NCHUNK - 1);

    __shared__ float posL[NPTS * 3];
    const float* pb = pos + b * (NPTS * 3);
    for (int i = threadIdx.x; i < NPTS * 3; i += 256) posL[i] = pb[i];
    __syncthreads();

    const float invD = (float)TN / (RMAX - R0);
    float acc = 0.0f;

    const int tend = (c + 1) * CHUNK;
    for (int t = c * CHUNK + (int)threadIdx.x; t < tend; t += 256) {
        int i, j;
        if (t < 130560) {
            const int d = (t >> 9) + 1;
            i = t & 511;
            j = (i + d) & 511;
        } else {
            i = t - 130560;
            j = i + 256;
        }
        const float dx = posL[3 * i    ] - posL[3 * j    ];
        const float dy = posL[3 * i + 1] - posL[3 * j + 1];
        const float dz = posL[3 * i + 2] - posL[3 * j + 2];
        const float r2 = fmaf(dx, dx, fmaf(dy, dy, dz * dz));
        const float r  = __builtin_amdgcn_sqrtf(r2);
        float x = (r - R0) * invD;
        x = fminf(fmaxf(x, 0.0f), (float)TN - 0.0005f);
        const int   idx = (int)x;
        const float f   = x - (float)idx;
        const float t0  = tab[idx];
        const float t1  = tab[idx + 1];
        acc = fmaf(f, t1 - t0, acc + t0);
    }

    #pragma unroll
    for (int o = 32; o; o >>= 1) acc += __shfl_xor(acc, o, 64);
    __shared__ float wsum[4];
    if ((threadIdx.x & 63) == 0) wsum[threadIdx.x >> 6] = acc;
    __syncthreads();
    if (threadIdx.x == 0)
        atomicAdd(out + b, wsum[0] + wsum[1] + wsum[2] + wsum[3]);
}

extern "C" void kernel_launch(void* const* d_in, const int* in_sizes, int n_in,
                              void* d_out, int out_size, void* d_ws, size_t ws_size,
                              hipStream_t stream) {
    const float* pos = (const float*)d_in[0];
    const float* W1  = (const float*)d_in[1];
    const float* b1  = (const float*)d_in[2];
    const float* W2  = (const float*)d_in[3];
    const float* b2  = (const float*)d_in[4];
    const float* W3  = (const float*)d_in[5];
    const float* b3  = (const float*)d_in[6];
    float*       out = (float*)d_out;
    float*       tab = (float*)d_ws;                 // (TN+1) floats = 32 KB

    // 257 blocks x 32 entries >= TN+1; also zeroes out[]
    table_kernel<<<dim3((TN + 1 + 31) / 32), dim3(256), 0, stream>>>(
        W1, b1, W2, b2, W3, b3, tab, out);

    // 8 batches x 128 chunks
    pair_sum_kernel<<<dim3(NBATCH * NCHUNK), dim3(256), 0, stream>>>(pos, tab, out);
}